// Round 1
// baseline (1026.079 us; speedup 1.0000x reference)
//
#include <hip/hip_runtime.h>
#include <math.h>

#define N_NODES 100000
#define N_EDGES 1600000
#define F_IN    16
#define H_DIM   32
#define B_GRAPHS 256

// ---------------------------------------------------------------------------
// deg[dst] += 1 over all edges (deg buffer pre-zeroed via memsetAsync)
__global__ void deg_kernel(const int* __restrict__ dst, float* __restrict__ deg) {
    int e = blockIdx.x * blockDim.x + threadIdx.x;
    if (e < N_EDGES) atomicAdd(&deg[dst[e]], 1.0f);
}

// deg -> dinv = rsqrt(deg + 1)  (in place; +1 is the self-loop)
__global__ void dinv_kernel(float* __restrict__ deg) {
    int i = blockIdx.x * blockDim.x + threadIdx.x;
    if (i < N_NODES) deg[i] = rsqrtf(deg[i] + 1.0f);
}

// ---------------------------------------------------------------------------
// hW = h @ W  (N x FIN @ FIN x 32), and initialize agg = hW*dinv^2 + b
// One thread per output element (i,j). W staged in LDS.
template <int FIN>
__global__ void matmul_self_kernel(const float* __restrict__ h,
                                   const float* __restrict__ W,
                                   const float* __restrict__ b,
                                   const float* __restrict__ dinv,
                                   float* __restrict__ hW,
                                   float* __restrict__ agg) {
    __shared__ float sW[FIN * H_DIM];
    for (int t = threadIdx.x; t < FIN * H_DIM; t += blockDim.x) sW[t] = W[t];
    __syncthreads();

    int idx = blockIdx.x * blockDim.x + threadIdx.x;
    if (idx >= N_NODES * H_DIM) return;  // grid is exact anyway (3.2M % 256 == 0)
    int i = idx >> 5;        // node
    int j = idx & 31;        // output feature

    const float* hrow = h + i * FIN;
    float acc = 0.f;
#pragma unroll
    for (int k = 0; k < FIN; ++k) acc += hrow[k] * sW[k * H_DIM + j];

    float di = dinv[i];
    hW[idx]  = acc;
    agg[idx] = acc * (di * di) + b[j];
}

// ---------------------------------------------------------------------------
// Edge aggregation: agg[dst, j] += hW[src, j] * dinv[src]*dinv[dst]
// 32 lanes per edge -> coalesced 128B gather + 32 contiguous atomics.
__global__ void scatter_kernel(const int* __restrict__ ei,
                               const float* __restrict__ dinv,
                               const float* __restrict__ hW,
                               float* __restrict__ agg) {
    int t = blockIdx.x * blockDim.x + threadIdx.x;   // < E*32 = 51.2M < 2^31
    if (t >= N_EDGES * H_DIM) return;
    int e = t >> 5;
    int j = t & 31;
    int s = ei[e];
    int d = ei[N_EDGES + e];
    float coef = dinv[s] * dinv[d];
    atomicAdd(&agg[d * H_DIM + j], hW[s * H_DIM + j] * coef);
}

// h = tanh(agg)
__global__ void tanh_kernel(const float* __restrict__ agg, float* __restrict__ h) {
    int i = blockIdx.x * blockDim.x + threadIdx.x;
    if (i < N_NODES * H_DIM) h[i] = tanhf(agg[i]);
}

// ---------------------------------------------------------------------------
// Per-graph pooling (batch_index sorted) + final linear head.
// One block per graph; binary search segment bounds; 8 node-lanes x 32 features.
__global__ void pool_kernel(const float* __restrict__ h,
                            const int* __restrict__ batch,
                            const float* __restrict__ Wout,
                            const float* __restrict__ bout,
                            float* __restrict__ out) {
    int b = blockIdx.x;
    int t = threadIdx.x;          // 256 threads
    int lane_n = t >> 5;          // 0..7
    int j = t & 31;               // feature

    // lower_bound(batch, b) and lower_bound(batch, b+1)
    int lo = 0, hi = N_NODES;
    while (lo < hi) { int mid = (lo + hi) >> 1; if (batch[mid] < b) lo = mid + 1; else hi = mid; }
    int start = lo;
    hi = N_NODES;
    while (lo < hi) { int mid = (lo + hi) >> 1; if (batch[mid] < b + 1) lo = mid + 1; else hi = mid; }
    int end = lo;

    float vmax = -INFINITY, vsum = 0.f;
    for (int i = start + lane_n; i < end; i += 8) {
        float v = h[i * H_DIM + j];
        vmax = fmaxf(vmax, v);
        vsum += v;
    }

    __shared__ float smax[8][32];
    __shared__ float ssum[8][32];
    __shared__ float pool96[96];
    smax[lane_n][j] = vmax;
    ssum[lane_n][j] = vsum;
    __syncthreads();

    if (t < 32) {
        float m = smax[0][t], s = ssum[0][t];
#pragma unroll
        for (int n = 1; n < 8; ++n) { m = fmaxf(m, smax[n][t]); s += ssum[n][t]; }
        int cnt = end - start;
        float mean = s / fmaxf((float)cnt, 1.0f);
        pool96[t]      = m;     // gmax
        pool96[32 + t] = mean;  // gmean
        pool96[64 + t] = s;     // gsum
    }
    __syncthreads();

    // pooled -> d_out (after the B "out" scalars)
    if (t < 96) out[B_GRAPHS + b * 96 + t] = pool96[t];

    // out[b] = pooled . W_out + b_out   (96-wide dot, one block => keep simple)
    __shared__ float dotbuf[96];
    if (t < 96) dotbuf[t] = pool96[t] * Wout[t];
    __syncthreads();
    if (t == 0) {
        float acc = 0.f;
#pragma unroll
        for (int k = 0; k < 96; ++k) acc += dotbuf[k];
        out[b] = acc + bout[0];
    }
}

// ---------------------------------------------------------------------------
extern "C" void kernel_launch(void* const* d_in, const int* in_sizes, int n_in,
                              void* d_out, int out_size, void* d_ws, size_t ws_size,
                              hipStream_t stream) {
    const float* x     = (const float*)d_in[0];
    const int*   ei    = (const int*)  d_in[1];   // [2,E]: src = ei[0:E], dst = ei[E:2E]
    const int*   batch = (const int*)  d_in[2];
    const float* W0    = (const float*)d_in[3];
    const float* b0    = (const float*)d_in[4];
    const float* W1    = (const float*)d_in[5];
    const float* b1    = (const float*)d_in[6];
    const float* W2    = (const float*)d_in[7];
    const float* b2    = (const float*)d_in[8];
    const float* W3    = (const float*)d_in[9];
    const float* b3    = (const float*)d_in[10];
    const float* Wout  = (const float*)d_in[11];
    const float* bout  = (const float*)d_in[12];
    float* out = (float*)d_out;

    float* ws   = (float*)d_ws;
    float* dinv = ws;                          // N
    float* hW   = dinv + N_NODES;              // N*H
    float* agg  = hW + N_NODES * H_DIM;        // N*H
    float* h    = agg + N_NODES * H_DIM;       // N*H

    hipMemsetAsync(dinv, 0, N_NODES * sizeof(float), stream);
    deg_kernel<<<(N_EDGES + 255) / 256, 256, 0, stream>>>(ei + N_EDGES, dinv);
    dinv_kernel<<<(N_NODES + 255) / 256, 256, 0, stream>>>(dinv);

    const int nh_blocks = (N_NODES * H_DIM) / 256;   // 12500 exact
    const int eh_blocks = (N_EDGES * H_DIM) / 256;   // 200000 exact

    // layer 0: F=16 -> 32
    matmul_self_kernel<F_IN><<<nh_blocks, 256, 0, stream>>>(x, W0, b0, dinv, hW, agg);
    scatter_kernel<<<eh_blocks, 256, 0, stream>>>(ei, dinv, hW, agg);
    tanh_kernel<<<nh_blocks, 256, 0, stream>>>(agg, h);

    // layers 1..3: 32 -> 32
    const float* Ws[3] = {W1, W2, W3};
    const float* bs[3] = {b1, b2, b3};
    for (int l = 0; l < 3; ++l) {
        matmul_self_kernel<H_DIM><<<nh_blocks, 256, 0, stream>>>(h, Ws[l], bs[l], dinv, hW, agg);
        scatter_kernel<<<eh_blocks, 256, 0, stream>>>(ei, dinv, hW, agg);
        tanh_kernel<<<nh_blocks, 256, 0, stream>>>(agg, h);
    }

    pool_kernel<<<B_GRAPHS, 256, 0, stream>>>(h, batch, Wout, bout, out);
}

// Round 2
// 726.263 us; speedup vs baseline: 1.4128x; 1.4128x over previous
//
#include <hip/hip_runtime.h>
#include <math.h>

#define N_NODES 100000
#define N_EDGES 1600000
#define F_IN    16
#define H_DIM   32
#define B_GRAPHS 256
#define NB      ((N_NODES + 255) / 256)   // 391 blocks over nodes

// ---------------------------------------------------------------------------
// counts[dst]++ over all edges (counts pre-zeroed via memsetAsync)
__global__ void count_kernel(const int* __restrict__ dst, int* __restrict__ counts) {
    int e = blockIdx.x * blockDim.x + threadIdx.x;
    if (e < N_EDGES) atomicAdd(&counts[dst[e]], 1);
}

// per-block sums of counts (256 per block)
__global__ void blocksum_kernel(const int* __restrict__ counts, int* __restrict__ bsum) {
    __shared__ int s[256];
    int i = blockIdx.x * 256 + threadIdx.x;
    s[threadIdx.x] = (i < N_NODES) ? counts[i] : 0;
    __syncthreads();
    for (int o = 128; o > 0; o >>= 1) {
        if (threadIdx.x < o) s[threadIdx.x] += s[threadIdx.x + o];
        __syncthreads();
    }
    if (threadIdx.x == 0) bsum[blockIdx.x] = s[0];
}

// exclusive scan of bsum[0..NB) in one block (NB=391 <= 512)
__global__ void scan_bsum_kernel(int* __restrict__ bsum) {
    __shared__ int s[512];
    int t = threadIdx.x;
    int v = (t < NB) ? bsum[t] : 0;
    s[t] = v;
    __syncthreads();
    for (int o = 1; o < 512; o <<= 1) {
        int add = (t >= o) ? s[t - o] : 0;
        __syncthreads();
        s[t] += add;
        __syncthreads();
    }
    if (t < NB) bsum[t] = s[t] - v;   // exclusive
}

// row_start = global exclusive scan; cursor = copy; dinv = rsqrt(count+1)
__global__ void finalize_kernel(const int* __restrict__ counts, const int* __restrict__ bsum,
                                int* __restrict__ row_start, int* __restrict__ cursor,
                                float* __restrict__ dinv) {
    __shared__ int s[256];
    int t = threadIdx.x;
    int i = blockIdx.x * 256 + t;
    int c = (i < N_NODES) ? counts[i] : 0;
    s[t] = c;
    __syncthreads();
    for (int o = 1; o < 256; o <<= 1) {
        int add = (t >= o) ? s[t - o] : 0;
        __syncthreads();
        s[t] += add;
        __syncthreads();
    }
    if (i < N_NODES) {
        int row = bsum[blockIdx.x] + s[t] - c;   // exclusive within block + block offset
        row_start[i] = row;
        cursor[i]    = row;
        dinv[i]      = rsqrtf((float)c + 1.0f);
    }
}

// fill CSR: for each edge, append (src, coef) to dst's segment
__global__ void fill_kernel(const int* __restrict__ ei, const float* __restrict__ dinv,
                            int* __restrict__ cursor,
                            int* __restrict__ csr_src, float* __restrict__ csr_coef) {
    int e = blockIdx.x * blockDim.x + threadIdx.x;
    if (e >= N_EDGES) return;
    int s = ei[e];
    int d = ei[N_EDGES + e];
    int pos = atomicAdd(&cursor[d], 1);
    csr_src[pos]  = s;
    csr_coef[pos] = dinv[s] * dinv[d];
}

// ---------------------------------------------------------------------------
// hW = h @ W  (N x FIN @ FIN x 32). One thread per (node, out-feature).
template <int FIN>
__global__ void matmul_kernel(const float* __restrict__ h,
                              const float* __restrict__ W,
                              float* __restrict__ hW) {
    __shared__ float sW[FIN * H_DIM];
    for (int t = threadIdx.x; t < FIN * H_DIM; t += blockDim.x) sW[t] = W[t];
    __syncthreads();

    int idx = blockIdx.x * blockDim.x + threadIdx.x;
    int i = idx >> 5;
    int j = idx & 31;
    if (i >= N_NODES) return;

    const float* hrow = h + i * FIN;
    float acc = 0.f;
#pragma unroll
    for (int k = 0; k < FIN; ++k) acc += hrow[k] * sW[k * H_DIM + j];
    hW[idx] = acc;
}

// ---------------------------------------------------------------------------
// Gather aggregation + self-loop + bias + tanh, fused.
// 32 lanes per node (one lane per feature); loop over incoming edges.
__global__ void gather_kernel(const int* __restrict__ row_start,
                              const int* __restrict__ counts,
                              const int* __restrict__ csr_src,
                              const float* __restrict__ csr_coef,
                              const float* __restrict__ dinv,
                              const float* __restrict__ hW,
                              const float* __restrict__ b,
                              float* __restrict__ h_out) {
    int t = blockIdx.x * blockDim.x + threadIdx.x;
    int i = t >> 5;        // node
    int j = t & 31;        // feature
    if (i >= N_NODES) return;

    int start = row_start[i];
    int cnt   = counts[i];
    float di  = dinv[i];
    float acc = hW[i * H_DIM + j] * (di * di);   // self-loop

    for (int e = start; e < start + cnt; ++e) {
        int   s = csr_src[e];     // broadcast across the 32-lane group
        float c = csr_coef[e];
        acc += hW[s * H_DIM + j] * c;
    }
    h_out[i * H_DIM + j] = tanhf(acc + b[j]);
}

// ---------------------------------------------------------------------------
// Per-graph pooling (batch_index sorted) + final linear head.
__global__ void pool_kernel(const float* __restrict__ h,
                            const int* __restrict__ batch,
                            const float* __restrict__ Wout,
                            const float* __restrict__ bout,
                            float* __restrict__ out) {
    int b = blockIdx.x;
    int t = threadIdx.x;          // 256 threads
    int lane_n = t >> 5;          // 0..7
    int j = t & 31;               // feature

    int lo = 0, hi = N_NODES;
    while (lo < hi) { int mid = (lo + hi) >> 1; if (batch[mid] < b) lo = mid + 1; else hi = mid; }
    int start = lo;
    hi = N_NODES;
    while (lo < hi) { int mid = (lo + hi) >> 1; if (batch[mid] < b + 1) lo = mid + 1; else hi = mid; }
    int end = lo;

    float vmax = -INFINITY, vsum = 0.f;
    for (int i = start + lane_n; i < end; i += 8) {
        float v = h[i * H_DIM + j];
        vmax = fmaxf(vmax, v);
        vsum += v;
    }

    __shared__ float smax[8][32];
    __shared__ float ssum[8][32];
    __shared__ float pool96[96];
    smax[lane_n][j] = vmax;
    ssum[lane_n][j] = vsum;
    __syncthreads();

    if (t < 32) {
        float m = smax[0][t], s = ssum[0][t];
#pragma unroll
        for (int n = 1; n < 8; ++n) { m = fmaxf(m, smax[n][t]); s += ssum[n][t]; }
        int cnt = end - start;
        float mean = s / fmaxf((float)cnt, 1.0f);
        pool96[t]      = m;
        pool96[32 + t] = mean;
        pool96[64 + t] = s;
    }
    __syncthreads();

    if (t < 96) out[B_GRAPHS + b * 96 + t] = pool96[t];

    __shared__ float dotbuf[96];
    if (t < 96) dotbuf[t] = pool96[t] * Wout[t];
    __syncthreads();
    if (t == 0) {
        float acc = 0.f;
#pragma unroll
        for (int k = 0; k < 96; ++k) acc += dotbuf[k];
        out[b] = acc + bout[0];
    }
}

// ---------------------------------------------------------------------------
extern "C" void kernel_launch(void* const* d_in, const int* in_sizes, int n_in,
                              void* d_out, int out_size, void* d_ws, size_t ws_size,
                              hipStream_t stream) {
    const float* x     = (const float*)d_in[0];
    const int*   ei    = (const int*)  d_in[1];   // [2,E]: src = ei[0:E], dst = ei[E:2E]
    const int*   batch = (const int*)  d_in[2];
    const float* W0    = (const float*)d_in[3];
    const float* b0    = (const float*)d_in[4];
    const float* W1    = (const float*)d_in[5];
    const float* b1    = (const float*)d_in[6];
    const float* W2    = (const float*)d_in[7];
    const float* b2    = (const float*)d_in[8];
    const float* W3    = (const float*)d_in[9];
    const float* b3    = (const float*)d_in[10];
    const float* Wout  = (const float*)d_in[11];
    const float* bout  = (const float*)d_in[12];
    float* out = (float*)d_out;

    // workspace layout (all 4-byte elements)
    char* p = (char*)d_ws;
    int*   counts    = (int*)p;            p += N_NODES * 4;
    int*   bsum      = (int*)p;            p += 512 * 4;
    int*   row_start = (int*)p;            p += N_NODES * 4;
    int*   cursor    = (int*)p;            p += N_NODES * 4;
    float* dinv      = (float*)p;          p += N_NODES * 4;
    int*   csr_src   = (int*)p;            p += N_EDGES * 4;
    float* csr_coef  = (float*)p;          p += N_EDGES * 4;
    float* hW        = (float*)p;          p += N_NODES * H_DIM * 4;
    float* h         = (float*)p;          p += N_NODES * H_DIM * 4;

    // ---- CSR build (once per launch, serves all 4 layers) ----
    hipMemsetAsync(counts, 0, N_NODES * sizeof(int), stream);
    count_kernel<<<(N_EDGES + 255) / 256, 256, 0, stream>>>(ei + N_EDGES, counts);
    blocksum_kernel<<<NB, 256, 0, stream>>>(counts, bsum);
    scan_bsum_kernel<<<1, 512, 0, stream>>>(bsum);
    finalize_kernel<<<NB, 256, 0, stream>>>(counts, bsum, row_start, cursor, dinv);
    fill_kernel<<<(N_EDGES + 255) / 256, 256, 0, stream>>>(ei, dinv, cursor, csr_src, csr_coef);

    const int nh_blocks = (N_NODES * H_DIM) / 256;   // 12500 exact

    // layer 0: F=16 -> 32
    matmul_kernel<F_IN><<<nh_blocks, 256, 0, stream>>>(x, W0, hW);
    gather_kernel<<<nh_blocks, 256, 0, stream>>>(row_start, counts, csr_src, csr_coef,
                                                 dinv, hW, b0, h);
    // layers 1..3: 32 -> 32
    const float* Ws[3] = {W1, W2, W3};
    const float* bs[3] = {b1, b2, b3};
    for (int l = 0; l < 3; ++l) {
        matmul_kernel<H_DIM><<<nh_blocks, 256, 0, stream>>>(h, Ws[l], hW);
        gather_kernel<<<nh_blocks, 256, 0, stream>>>(row_start, counts, csr_src, csr_coef,
                                                     dinv, hW, bs[l], h);
    }

    pool_kernel<<<B_GRAPHS, 256, 0, stream>>>(h, batch, Wout, bout, out);
}

// Round 3
// 655.220 us; speedup vs baseline: 1.5660x; 1.1084x over previous
//
#include <hip/hip_runtime.h>
#include <math.h>

#define N_NODES 100000
#define N_EDGES 1600000
#define F_IN    16
#define H_DIM   32
#define B_GRAPHS 256
#define NB      ((N_NODES + 255) / 256)     // 391
#define NPB     16                           // nodes per block in layer kernels
#define LAYER_BLOCKS (N_NODES / NPB)         // 6250 exact

// ---------------------------------------------------------------------------
// bf16x2 helpers: packed uint <-> two floats
__device__ inline float bf_lo(unsigned u) { return __uint_as_float(u << 16); }
__device__ inline float bf_hi(unsigned u) { return __uint_as_float(u & 0xffff0000u); }
__device__ inline unsigned pack_bf16x2(float a, float b) {
    unsigned ua = __float_as_uint(a), ub = __float_as_uint(b);
    ua += 0x7fffu + ((ua >> 16) & 1u);       // round-to-nearest-even
    ub += 0x7fffu + ((ub >> 16) & 1u);
    return (ua >> 16) | (ub & 0xffff0000u);
}

// ---------------------------------------------------------------------------
// counts[dst]++ (counts pre-zeroed)
__global__ void count_kernel(const int* __restrict__ dst, int* __restrict__ counts) {
    int e = blockIdx.x * blockDim.x + threadIdx.x;
    if (e < N_EDGES) atomicAdd(&counts[dst[e]], 1);
}

__global__ void blocksum_kernel(const int* __restrict__ counts, int* __restrict__ bsum) {
    __shared__ int s[256];
    int i = blockIdx.x * 256 + threadIdx.x;
    s[threadIdx.x] = (i < N_NODES) ? counts[i] : 0;
    __syncthreads();
    for (int o = 128; o > 0; o >>= 1) {
        if (threadIdx.x < o) s[threadIdx.x] += s[threadIdx.x + o];
        __syncthreads();
    }
    if (threadIdx.x == 0) bsum[blockIdx.x] = s[0];
}

__global__ void scan_bsum_kernel(int* __restrict__ bsum) {
    __shared__ int s[512];
    int t = threadIdx.x;
    int v = (t < NB) ? bsum[t] : 0;
    s[t] = v;
    __syncthreads();
    for (int o = 1; o < 512; o <<= 1) {
        int add = (t >= o) ? s[t - o] : 0;
        __syncthreads();
        s[t] += add;
        __syncthreads();
    }
    if (t < NB) bsum[t] = s[t] - v;   // exclusive
}

__global__ void finalize_kernel(const int* __restrict__ counts, const int* __restrict__ bsum,
                                int* __restrict__ row_start, int* __restrict__ cursor,
                                float* __restrict__ dinv) {
    __shared__ int s[256];
    int t = threadIdx.x;
    int i = blockIdx.x * 256 + t;
    int c = (i < N_NODES) ? counts[i] : 0;
    s[t] = c;
    __syncthreads();
    for (int o = 1; o < 256; o <<= 1) {
        int add = (t >= o) ? s[t - o] : 0;
        __syncthreads();
        s[t] += add;
        __syncthreads();
    }
    if (i < N_NODES) {
        int row = bsum[blockIdx.x] + s[t] - c;
        row_start[i] = row;
        cursor[i]    = row;
        dinv[i]      = rsqrtf((float)c + 1.0f);
    }
}

// fill CSR: only src index (coef recomputed in layer kernels from dinv)
__global__ void fill_kernel(const int* __restrict__ ei, int* __restrict__ cursor,
                            int* __restrict__ csr_src) {
    int e = blockIdx.x * blockDim.x + threadIdx.x;
    if (e >= N_EDGES) return;
    int s = ei[e];
    int d = ei[N_EDGES + e];
    int pos = atomicAdd(&cursor[d], 1);
    csr_src[pos] = s;
}

// ---------------------------------------------------------------------------
// Layer 0: aggregate raw x (f32, 16 feats) then apply W0 [16x32] + b0, tanh,
// write bf16x2-packed h. 16 lanes per node, 16 nodes per 256-thread block.
__global__ __launch_bounds__(256) void gcn_layer0_kernel(
        const float* __restrict__ x,
        const int* __restrict__ row_start, const int* __restrict__ counts,
        const int* __restrict__ csr_src, const float* __restrict__ dinv,
        const float* __restrict__ W, const float* __restrict__ bias,
        unsigned* __restrict__ h_out) {
    __shared__ float sW[F_IN * H_DIM];      // 512
    __shared__ float sb[H_DIM];
    __shared__ float agg[NPB][F_IN + 1];
    int t = threadIdx.x;
    for (int k = t; k < F_IN * H_DIM; k += 256) sW[k] = W[k];
    if (t < H_DIM) sb[t] = bias[t];

    int nl = t >> 4, ln = t & 15;
    int i = blockIdx.x * NPB + nl;
    int start = row_start[i];
    int cnt   = counts[i];
    float di  = dinv[i];
    float acc = x[i * F_IN + ln] * (di * di);     // self-loop
    for (int e = 0; e < cnt; ++e) {
        int s = csr_src[start + e];               // broadcast within 16-lane group
        float c = dinv[s] * di;
        acc += x[s * F_IN + ln] * c;
    }
    agg[nl][ln] = acc;
    __syncthreads();

    int j0 = 2 * ln;
    float o0 = sb[j0], o1 = sb[j0 + 1];
#pragma unroll
    for (int k = 0; k < F_IN; ++k) {
        float a = agg[nl][k];
        o0 += a * sW[k * H_DIM + j0];
        o1 += a * sW[k * H_DIM + j0 + 1];
    }
    o0 = tanhf(o0); o1 = tanhf(o1);
    h_out[i * 16 + ln] = pack_bf16x2(o0, o1);
}

// Layers 1..3: aggregate bf16x2-packed h (32 feats = 64B/row), apply W [32x32]
// + b, tanh. Optionally also write f32 h (final layer, for pooling).
__global__ __launch_bounds__(256) void gcn_layer_kernel(
        const unsigned* __restrict__ h_in,
        const int* __restrict__ row_start, const int* __restrict__ counts,
        const int* __restrict__ csr_src, const float* __restrict__ dinv,
        const float* __restrict__ W, const float* __restrict__ bias,
        unsigned* __restrict__ h_out, float* __restrict__ h_f32) {
    __shared__ float sW[H_DIM * H_DIM];     // 1024
    __shared__ float sb[H_DIM];
    __shared__ float agg[NPB][H_DIM + 1];
    int t = threadIdx.x;
    for (int k = t; k < H_DIM * H_DIM; k += 256) sW[k] = W[k];
    if (t < H_DIM) sb[t] = bias[t];

    int nl = t >> 4, ln = t & 15;
    int i = blockIdx.x * NPB + nl;
    int start = row_start[i];
    int cnt   = counts[i];
    float di  = dinv[i];
    float di2 = di * di;
    unsigned u = h_in[i * 16 + ln];
    float acc0 = bf_lo(u) * di2, acc1 = bf_hi(u) * di2;   // self-loop
    for (int e = 0; e < cnt; ++e) {
        int s = csr_src[start + e];
        float c = dinv[s] * di;
        unsigned v = h_in[s * 16 + ln];
        acc0 += bf_lo(v) * c;
        acc1 += bf_hi(v) * c;
    }
    agg[nl][2 * ln]     = acc0;
    agg[nl][2 * ln + 1] = acc1;
    __syncthreads();

    int j0 = 2 * ln;
    float o0 = sb[j0], o1 = sb[j0 + 1];
#pragma unroll
    for (int k = 0; k < H_DIM; ++k) {
        float a = agg[nl][k];
        o0 += a * sW[k * H_DIM + j0];
        o1 += a * sW[k * H_DIM + j0 + 1];
    }
    o0 = tanhf(o0); o1 = tanhf(o1);
    h_out[i * 16 + ln] = pack_bf16x2(o0, o1);
    if (h_f32) {
        h_f32[i * H_DIM + j0]     = o0;
        h_f32[i * H_DIM + j0 + 1] = o1;
    }
}

// ---------------------------------------------------------------------------
// Per-graph pooling (batch sorted) + linear head.
__global__ void pool_kernel(const float* __restrict__ h,
                            const int* __restrict__ batch,
                            const float* __restrict__ Wout,
                            const float* __restrict__ bout,
                            float* __restrict__ out) {
    int b = blockIdx.x;
    int t = threadIdx.x;
    int lane_n = t >> 5;
    int j = t & 31;

    int lo = 0, hi = N_NODES;
    while (lo < hi) { int mid = (lo + hi) >> 1; if (batch[mid] < b) lo = mid + 1; else hi = mid; }
    int start = lo;
    hi = N_NODES;
    while (lo < hi) { int mid = (lo + hi) >> 1; if (batch[mid] < b + 1) lo = mid + 1; else hi = mid; }
    int end = lo;

    float vmax = -INFINITY, vsum = 0.f;
    for (int i = start + lane_n; i < end; i += 8) {
        float v = h[i * H_DIM + j];
        vmax = fmaxf(vmax, v);
        vsum += v;
    }

    __shared__ float smax[8][32];
    __shared__ float ssum[8][32];
    __shared__ float pool96[96];
    smax[lane_n][j] = vmax;
    ssum[lane_n][j] = vsum;
    __syncthreads();

    if (t < 32) {
        float m = smax[0][t], s = ssum[0][t];
#pragma unroll
        for (int n = 1; n < 8; ++n) { m = fmaxf(m, smax[n][t]); s += ssum[n][t]; }
        int cnt = end - start;
        float mean = s / fmaxf((float)cnt, 1.0f);
        pool96[t]      = m;
        pool96[32 + t] = mean;
        pool96[64 + t] = s;
    }
    __syncthreads();

    if (t < 96) out[B_GRAPHS + b * 96 + t] = pool96[t];

    __shared__ float dotbuf[96];
    if (t < 96) dotbuf[t] = pool96[t] * Wout[t];
    __syncthreads();
    if (t == 0) {
        float acc = 0.f;
#pragma unroll
        for (int k = 0; k < 96; ++k) acc += dotbuf[k];
        out[b] = acc + bout[0];
    }
}

// ---------------------------------------------------------------------------
extern "C" void kernel_launch(void* const* d_in, const int* in_sizes, int n_in,
                              void* d_out, int out_size, void* d_ws, size_t ws_size,
                              hipStream_t stream) {
    const float* x     = (const float*)d_in[0];
    const int*   ei    = (const int*)  d_in[1];
    const int*   batch = (const int*)  d_in[2];
    const float* W0    = (const float*)d_in[3];
    const float* b0    = (const float*)d_in[4];
    const float* W1    = (const float*)d_in[5];
    const float* b1    = (const float*)d_in[6];
    const float* W2    = (const float*)d_in[7];
    const float* b2    = (const float*)d_in[8];
    const float* W3    = (const float*)d_in[9];
    const float* b3    = (const float*)d_in[10];
    const float* Wout  = (const float*)d_in[11];
    const float* bout  = (const float*)d_in[12];
    float* out = (float*)d_out;

    char* p = (char*)d_ws;
    int*      counts    = (int*)p;       p += N_NODES * 4;
    int*      bsum      = (int*)p;       p += 512 * 4;
    int*      row_start = (int*)p;       p += N_NODES * 4;
    int*      cursor    = (int*)p;       p += N_NODES * 4;
    float*    dinv      = (float*)p;     p += N_NODES * 4;
    int*      csr_src   = (int*)p;       p += N_EDGES * 4;
    unsigned* hA        = (unsigned*)p;  p += N_NODES * 16 * 4;
    unsigned* hB        = (unsigned*)p;  p += N_NODES * 16 * 4;
    float*    h_f32     = (float*)p;     p += N_NODES * H_DIM * 4;

    // ---- CSR build (serves all 4 layers) ----
    hipMemsetAsync(counts, 0, N_NODES * sizeof(int), stream);
    count_kernel<<<(N_EDGES + 255) / 256, 256, 0, stream>>>(ei + N_EDGES, counts);
    blocksum_kernel<<<NB, 256, 0, stream>>>(counts, bsum);
    scan_bsum_kernel<<<1, 512, 0, stream>>>(bsum);
    finalize_kernel<<<NB, 256, 0, stream>>>(counts, bsum, row_start, cursor, dinv);
    fill_kernel<<<(N_EDGES + 255) / 256, 256, 0, stream>>>(ei, cursor, csr_src);

    // ---- 4 GCN layers, aggregate-then-transform, bf16 h between layers ----
    gcn_layer0_kernel<<<LAYER_BLOCKS, 256, 0, stream>>>(
        x, row_start, counts, csr_src, dinv, W0, b0, hA);
    gcn_layer_kernel<<<LAYER_BLOCKS, 256, 0, stream>>>(
        hA, row_start, counts, csr_src, dinv, W1, b1, hB, (float*)nullptr);
    gcn_layer_kernel<<<LAYER_BLOCKS, 256, 0, stream>>>(
        hB, row_start, counts, csr_src, dinv, W2, b2, hA, (float*)nullptr);
    gcn_layer_kernel<<<LAYER_BLOCKS, 256, 0, stream>>>(
        hA, row_start, counts, csr_src, dinv, W3, b3, hB, h_f32);

    pool_kernel<<<B_GRAPHS, 256, 0, stream>>>(h_f32, batch, Wout, bout, out);
}